// Round 3
// baseline (5791.971 us; speedup 1.0000x reference)
//
#include <hip/hip_runtime.h>

typedef unsigned short u16;
typedef unsigned int u32;
typedef __attribute__((ext_vector_type(8))) short bf16x8;
typedef __attribute__((ext_vector_type(4))) float f32x4;
typedef __attribute__((ext_vector_type(2))) u32 u32x2;
typedef const __attribute__((address_space(1))) void* gas1_t;
typedef __attribute__((address_space(3))) void* las3_t;

// Problem dims
#define T_LEN 512
#define B_SZ  64
#define D_SZ  1024
#define H_SZ  1024

// workspace layout (bytes), all 256-aligned
#define OFF_WX    0UL          // 8 MiB  bf16 Wx  [4096][1024]
#define OFF_WH    8388608UL    // 8 MiB  bf16 Wh  [4096][1024]
#define OFF_BIAS  16777216UL   // 16 KiB f32 bias[4096] = bx+bh
#define OFF_HBUF  16793600UL   // 256 KiB bf16 hbuf[2][64][1024]
#define OFF_FLAGS 17055744UL   // 1 KiB  u32 flags[2][128] (per-batch-half barriers)
#define OFF_XBF   17056768UL   // 64 MiB bf16 x [32768][1024]
#define OFF_XPROJ 84165632UL   // 256 MiB bf16 xproj [32768][4096]

__device__ __forceinline__ u16 f2bf(float f) {
  u32 u = __builtin_bit_cast(u32, f);
  u += 0x7FFFu + ((u >> 16) & 1u);   // RNE
  return (u16)(u >> 16);
}
__device__ __forceinline__ float bf2f(u16 h) {
  u32 u = ((u32)h) << 16;
  return __builtin_bit_cast(float, u);
}

// ---------- phase 0: conversions ----------
__global__ __launch_bounds__(256) void cvt_f32_bf16(const float* __restrict__ in,
                                                    u16* __restrict__ out, int n) {
  int i = (blockIdx.x * 256 + threadIdx.x) * 4;
  if (i >= n) return;
  float4 v = *(const float4*)(in + i);
  ushort4 o;
  o.x = f2bf(v.x); o.y = f2bf(v.y); o.z = f2bf(v.z); o.w = f2bf(v.w);
  *(ushort4*)(out + i) = o;
}

__global__ __launch_bounds__(256) void bias_add(const float* __restrict__ a,
                                                const float* __restrict__ b,
                                                float* __restrict__ o) {
  int i = blockIdx.x * 256 + threadIdx.x;  // 4096 total
  o[i] = a[i] + b[i];
}

// ---------- phase 1: xproj = x @ Wx^T (bf16 MFMA, 128x128 tile, BK=64) ----------
__global__ __launch_bounds__(256) void gemm_xproj(const u16* __restrict__ A,
                                                  const u16* __restrict__ Bw,
                                                  u16* __restrict__ C) {
  __shared__ __align__(16) u16 As[128 * 64];
  __shared__ __align__(16) u16 Bs[128 * 64];
  int wg = blockIdx.x;
  int swz = (wg & 7) * 1024 + (wg >> 3);  // XCD-aware bijective (8192 % 8 == 0)
  int mb = swz >> 5;
  int nb = swz & 31;
  int tid = threadIdx.x;
  int lane = tid & 63;
  int w = tid >> 6;
  int wm = w >> 1, wn = w & 1;

  int srow = lane >> 3;
  int scol = (lane & 7) * 8;
  const u16* Abase = A + (size_t)(mb * 128) * 1024;
  const u16* Bbase = Bw + (size_t)(nb * 128) * 1024;

  f32x4 acc[4][4];
#pragma unroll
  for (int i = 0; i < 4; ++i)
#pragma unroll
    for (int j = 0; j < 4; ++j) acc[i][j] = f32x4{0.f, 0.f, 0.f, 0.f};

  for (int k0 = 0; k0 < 1024; k0 += 64) {
#pragma unroll
    for (int r = 0; r < 4; ++r) {
      int chunk = w * 4 + r;
      int row = chunk * 8 + srow;
      __builtin_amdgcn_global_load_lds((gas1_t)(const void*)(Abase + (size_t)row * 1024 + k0 + scol),
                                       (las3_t)(void*)(&As[chunk * 512]), 16, 0, 0);
      __builtin_amdgcn_global_load_lds((gas1_t)(const void*)(Bbase + (size_t)row * 1024 + k0 + scol),
                                       (las3_t)(void*)(&Bs[chunk * 512]), 16, 0, 0);
    }
    __syncthreads();
#pragma unroll
    for (int kk = 0; kk < 64; kk += 32) {
      bf16x8 af[4], bfr[4];
#pragma unroll
      for (int mt = 0; mt < 4; ++mt)
        af[mt] = *(const bf16x8*)&As[(wm * 64 + mt * 16 + (lane & 15)) * 64 + kk + ((lane >> 4) << 3)];
#pragma unroll
      for (int nt = 0; nt < 4; ++nt)
        bfr[nt] = *(const bf16x8*)&Bs[(wn * 64 + nt * 16 + (lane & 15)) * 64 + kk + ((lane >> 4) << 3)];
#pragma unroll
      for (int mt = 0; mt < 4; ++mt)
#pragma unroll
        for (int nt = 0; nt < 4; ++nt)
          acc[mt][nt] = __builtin_amdgcn_mfma_f32_16x16x32_bf16(af[mt], bfr[nt], acc[mt][nt], 0, 0, 0);
    }
    __syncthreads();
  }
  int crowbase = mb * 128 + wm * 64;
  int ccolbase = nb * 128 + wn * 64;
#pragma unroll
  for (int mt = 0; mt < 4; ++mt)
#pragma unroll
    for (int nt = 0; nt < 4; ++nt) {
      int col = ccolbase + nt * 16 + (lane & 15);
#pragma unroll
      for (int r = 0; r < 4; ++r) {
        int row = crowbase + mt * 16 + ((lane >> 4) << 2) + r;
        C[(size_t)row * 4096 + col] = f2bf(acc[mt][nt][r]);
      }
    }
}

// ---------- phase 2: persistent sequential LSTM ----------
// Two INDEPENDENT 128-WG systems (batch halves never interact).
// h stores: write-through sc0 sc1 (nothing dirty in L2 -> no wbl2 ever).
// h loads: NORMAL cached loads after fence(acquire, agent) (= buffer_inv tag
// flash) -> each XCD fetches h from LLC once, its WGs hit L2 (16x dedup).
// Flags polled sc0 sc1 (8 lines per half) with s_sleep backoff.
__global__ __launch_bounds__(256) void lstm_seq(const u16* __restrict__ xproj,
                                                const u16* __restrict__ Whb,
                                                const float* __restrict__ bias,
                                                u16* __restrict__ hbuf,
                                                u32* __restrict__ flags,
                                                float* __restrict__ out) {
  // pacc rows padded 16->17 floats: ds_write conflict-free, ds_read <=2-way
  __shared__ float pacc[16 * 272];
#define PIDX(frag, row, col) (((frag) * 272) + (row) * 17 + (col))
  int wg = blockIdx.x;
  int bh = wg >> 7;       // batch half (independent system)
  int hs = wg & 127;      // h-col slice (8 cols)
  int tid = threadIdx.x;
  int lane = tid & 63;
  int w = tid >> 6;       // wave -> K-slice
  int kw = w << 8;        // k base (256 per wave)
  int hi8 = (lane >> 4) << 3;

  // preload Wh fragments (register-resident for all 512 steps)
  bf16x8 wf[2][8];
#pragma unroll
  for (int nt = 0; nt < 2; ++nt) {
    int c = nt * 16 + (lane & 15);
    int wrow = ((c >> 3) << 10) + (hs << 3) + (c & 7);  // gate*1024 + hs*8 + jj
#pragma unroll
    for (int ks = 0; ks < 8; ++ks)
      wf[nt][ks] = *(const bf16x8*)&Whb[(size_t)wrow * 1024 + kw + ks * 32 + hi8];
  }

  int b = tid >> 3;                  // 0..31 batch row within half
  int jj = tid & 7;                  // h-col within slice
  int hrow = (bh << 5) + b;
  int hcol = (hs << 3) + jj;
  float bs0 = bias[hcol], bs1 = bias[1024 + hcol], bs2 = bias[2048 + hcol], bs3 = bias[3072 + hcol];
  float c_state = 0.f;
  int am_row0 = (bh << 5) + (lane & 15);
  int am_row1 = am_row0 + 16;
  int mI = b >> 4, r16 = b & 15;
  u32* myflags = flags + (bh << 7);  // 128 dwords for this half

  for (int t = 0; t < T_LEN; ++t) {
    const u16* hcur = hbuf + (size_t)(t & 1) * 65536;
    // xproj: normal cached loads (immutable)
    const u16* xp = xproj + ((size_t)(t * 64 + hrow)) * 4096;
    u16 xp0 = xp[hcol], xp1 = xp[1024 + hcol], xp2 = xp[2048 + hcol], xp3 = xp[3072 + hcol];

    // h loads: normal cached (L1/L2 were invalidated by last step's acquire)
    const u16* p0 = hcur + (size_t)am_row0 * 1024 + kw + hi8;
    const u16* p1 = hcur + (size_t)am_row1 * 1024 + kw + hi8;
    bf16x8 a0s[8], a1s[8];
#pragma unroll
    for (int ks = 0; ks < 8; ++ks) {
      a0s[ks] = *(const bf16x8*)(p0 + ks * 32);
      a1s[ks] = *(const bf16x8*)(p1 + ks * 32);
    }

    f32x4 acc00 = f32x4{0.f, 0.f, 0.f, 0.f}, acc01 = acc00, acc10 = acc00, acc11 = acc00;
#pragma unroll
    for (int ks = 0; ks < 8; ++ks) {
      acc00 = __builtin_amdgcn_mfma_f32_16x16x32_bf16(a0s[ks], wf[0][ks], acc00, 0, 0, 0);
      acc01 = __builtin_amdgcn_mfma_f32_16x16x32_bf16(a0s[ks], wf[1][ks], acc01, 0, 0, 0);
      acc10 = __builtin_amdgcn_mfma_f32_16x16x32_bf16(a1s[ks], wf[0][ks], acc10, 0, 0, 0);
      acc11 = __builtin_amdgcn_mfma_f32_16x16x32_bf16(a1s[ks], wf[1][ks], acc11, 0, 0, 0);
    }
    // per-wave partials -> LDS (padded)
    {
      int rbase = ((lane >> 4) << 2);
      int cidx = lane & 15;
#pragma unroll
      for (int r = 0; r < 4; ++r) {
        pacc[PIDX(w * 4 + 0, rbase + r, cidx)] = acc00[r];
        pacc[PIDX(w * 4 + 1, rbase + r, cidx)] = acc01[r];
        pacc[PIDX(w * 4 + 2, rbase + r, cidx)] = acc10[r];
        pacc[PIDX(w * 4 + 3, rbase + r, cidx)] = acc11[r];
      }
    }
    __syncthreads();
    float g[4];
#pragma unroll
    for (int gate = 0; gate < 4; ++gate) {
      int cc = gate * 8 + jj;
      int nt = cc >> 4, c16 = cc & 15;
      float s = 0.f;
#pragma unroll
      for (int w2 = 0; w2 < 4; ++w2)
        s += pacc[PIDX(w2 * 4 + mI * 2 + nt, r16, c16)];
      g[gate] = s;
    }
    float gi = g[0] + bf2f(xp0) + bs0;
    float gf = g[1] + bf2f(xp1) + bs1;
    float go = g[2] + bf2f(xp2) + bs2;
    float gc = g[3] + bf2f(xp3) + bs3;
    float iv = 1.f / (1.f + __expf(-gi));
    float fv = 1.f / (1.f + __expf(-gf));
    float ov = 1.f / (1.f + __expf(-go));
    float cv = tanhf(gc);
    c_state = 1.f / (1.f + __expf(-(fv * c_state + iv * cv)));  // nonstandard, per reference
    float hn = tanhf(c_state) * ov;

    if (t == T_LEN - 1) {
      out[(size_t)hrow * 1024 + hcol] = hn;
    } else {
      // write-through h store to LLC + own-wave drain
      u16* hdst = hbuf + (size_t)((t & 1) ^ 1) * 65536 + (size_t)hrow * 1024 + hcol;
      u32 hb = (u32)f2bf(hn);
      asm volatile("global_store_short %0, %1, off sc0 sc1" :: "v"(hdst), "v"(hb) : "memory");
      asm volatile("s_waitcnt vmcnt(0)" ::: "memory");
      __syncthreads();  // all 4 waves' stores drained; pacc reads done
      u32 tgt = (u32)(t + 1);
      if (tid == 0) {
        u32* fp = myflags + hs;
        asm volatile("global_store_dword %0, %1, off sc0 sc1" :: "v"(fp), "v"(tgt) : "memory");
      }
      if (tid < 64) {
        const u32* fp = myflags + (tid << 1);
        for (;;) {
          u32x2 f;
          asm volatile("global_load_dwordx2 %0, %1, off sc0 sc1\n\ts_waitcnt vmcnt(0)"
                       : "=v"(f) : "v"(fp) : "memory");
          if (__all((f[0] >= tgt) && (f[1] >= tgt))) break;
          __builtin_amdgcn_s_sleep(2);
        }
        // acquire: invalidate L1 + this XCD's L2 so next h loads see fresh data
        __builtin_amdgcn_fence(__ATOMIC_ACQUIRE, "agent");
      }
      __syncthreads();
    }
  }
}

extern "C" void kernel_launch(void* const* d_in, const int* in_sizes, int n_in,
                              void* d_out, int out_size, void* d_ws, size_t ws_size,
                              hipStream_t stream) {
  const float* x  = (const float*)d_in[0];   // [512][64][1024]
  const float* Wx = (const float*)d_in[1];   // [4][1024][1024]
  const float* bx = (const float*)d_in[2];   // [4][1024]
  const float* Wh = (const float*)d_in[3];   // [4][1024][1024]
  const float* bh = (const float*)d_in[4];   // [4][1024]
  float* out = (float*)d_out;                // [64][1024]
  char* ws = (char*)d_ws;

  u16* wx_bf  = (u16*)(ws + OFF_WX);
  u16* wh_bf  = (u16*)(ws + OFF_WH);
  float* bias = (float*)(ws + OFF_BIAS);
  u16* hbuf   = (u16*)(ws + OFF_HBUF);
  u32* flags  = (u32*)(ws + OFF_FLAGS);
  u16* x_bf   = (u16*)(ws + OFF_XBF);
  u16* xproj  = (u16*)(ws + OFF_XPROJ);

  // zero hbuf[0..1] + flags (contiguous 263168 bytes)
  hipMemsetAsync(ws + OFF_HBUF, 0, 263168, stream);

  cvt_f32_bf16<<<4096, 256, 0, stream>>>(Wx, wx_bf, 4194304);
  cvt_f32_bf16<<<4096, 256, 0, stream>>>(Wh, wh_bf, 4194304);
  bias_add<<<16, 256, 0, stream>>>(bx, bh, bias);
  cvt_f32_bf16<<<32768, 256, 0, stream>>>(x, x_bf, 33554432);
  gemm_xproj<<<8192, 256, 0, stream>>>(x_bf, wx_bf, xproj);
  lstm_seq<<<256, 256, 0, stream>>>(xproj, wh_bf, bias, hbuf, flags, out);
}

// Round 4
// 5410.634 us; speedup vs baseline: 1.0705x; 1.0705x over previous
//
#include <hip/hip_runtime.h>

typedef unsigned short u16;
typedef unsigned int u32;
typedef __attribute__((ext_vector_type(8))) short bf16x8;
typedef __attribute__((ext_vector_type(4))) float f32x4;
typedef __attribute__((ext_vector_type(2))) u32 u32x2;
typedef __attribute__((ext_vector_type(4))) u32 u32x4;
typedef const __attribute__((address_space(1))) void* gas1_t;
typedef __attribute__((address_space(3))) void* las3_t;

// Problem dims
#define T_LEN 512
#define B_SZ  64
#define D_SZ  1024
#define H_SZ  1024

// workspace layout (bytes), all 256-aligned
#define OFF_WX    0UL           // 8 MiB  bf16 Wx  [4096][1024]
#define OFF_WH    8388608UL     // 8 MiB  bf16 Wh  [4096][1024]
#define OFF_BIAS  16777216UL    // 16 KiB f32 bias[4096] = bx+bh
#define OFF_FLAGS 16793600UL    // 1 KiB  u32 flags[2][128] (per-batch-half barriers)
#define OFF_HROLL 16794624UL    // 64 MiB bf16 hroll[512][64][1024] (rolling, slot t = h input of step t)
#define OFF_XBF   83903488UL    // 64 MiB bf16 x [32768][1024]
#define OFF_XPROJ 151012352UL   // 256 MiB bf16 xproj [32768][4096]

__device__ __forceinline__ u16 f2bf(float f) {
  u32 u = __builtin_bit_cast(u32, f);
  u += 0x7FFFu + ((u >> 16) & 1u);   // RNE
  return (u16)(u >> 16);
}
__device__ __forceinline__ float bf2f(u16 h) {
  u32 u = ((u32)h) << 16;
  return __builtin_bit_cast(float, u);
}

// ---------- phase 0: conversions ----------
__global__ __launch_bounds__(256) void cvt_f32_bf16(const float* __restrict__ in,
                                                    u16* __restrict__ out, int n) {
  int i = (blockIdx.x * 256 + threadIdx.x) * 4;
  if (i >= n) return;
  float4 v = *(const float4*)(in + i);
  ushort4 o;
  o.x = f2bf(v.x); o.y = f2bf(v.y); o.z = f2bf(v.z); o.w = f2bf(v.w);
  *(ushort4*)(out + i) = o;
}

__global__ __launch_bounds__(256) void bias_add(const float* __restrict__ a,
                                                const float* __restrict__ b,
                                                float* __restrict__ o) {
  int i = blockIdx.x * 256 + threadIdx.x;  // 4096 total
  o[i] = a[i] + b[i];
}

// ---------- phase 1: xproj = x @ Wx^T (bf16 MFMA, 128x128 tile, BK=64) ----------
__global__ __launch_bounds__(256) void gemm_xproj(const u16* __restrict__ A,
                                                  const u16* __restrict__ Bw,
                                                  u16* __restrict__ C) {
  __shared__ __align__(16) u16 As[128 * 64];
  __shared__ __align__(16) u16 Bs[128 * 64];
  int wg = blockIdx.x;
  int swz = (wg & 7) * 1024 + (wg >> 3);  // XCD-aware bijective (8192 % 8 == 0)
  int mb = swz >> 5;
  int nb = swz & 31;
  int tid = threadIdx.x;
  int lane = tid & 63;
  int w = tid >> 6;
  int wm = w >> 1, wn = w & 1;

  int srow = lane >> 3;
  int scol = (lane & 7) * 8;
  const u16* Abase = A + (size_t)(mb * 128) * 1024;
  const u16* Bbase = Bw + (size_t)(nb * 128) * 1024;

  f32x4 acc[4][4];
#pragma unroll
  for (int i = 0; i < 4; ++i)
#pragma unroll
    for (int j = 0; j < 4; ++j) acc[i][j] = f32x4{0.f, 0.f, 0.f, 0.f};

  for (int k0 = 0; k0 < 1024; k0 += 64) {
#pragma unroll
    for (int r = 0; r < 4; ++r) {
      int chunk = w * 4 + r;
      int row = chunk * 8 + srow;
      __builtin_amdgcn_global_load_lds((gas1_t)(const void*)(Abase + (size_t)row * 1024 + k0 + scol),
                                       (las3_t)(void*)(&As[chunk * 512]), 16, 0, 0);
      __builtin_amdgcn_global_load_lds((gas1_t)(const void*)(Bbase + (size_t)row * 1024 + k0 + scol),
                                       (las3_t)(void*)(&Bs[chunk * 512]), 16, 0, 0);
    }
    __syncthreads();
#pragma unroll
    for (int kk = 0; kk < 64; kk += 32) {
      bf16x8 af[4], bfr[4];
#pragma unroll
      for (int mt = 0; mt < 4; ++mt)
        af[mt] = *(const bf16x8*)&As[(wm * 64 + mt * 16 + (lane & 15)) * 64 + kk + ((lane >> 4) << 3)];
#pragma unroll
      for (int nt = 0; nt < 4; ++nt)
        bfr[nt] = *(const bf16x8*)&Bs[(wn * 64 + nt * 16 + (lane & 15)) * 64 + kk + ((lane >> 4) << 3)];
#pragma unroll
      for (int mt = 0; mt < 4; ++mt)
#pragma unroll
        for (int nt = 0; nt < 4; ++nt)
          acc[mt][nt] = __builtin_amdgcn_mfma_f32_16x16x32_bf16(af[mt], bfr[nt], acc[mt][nt], 0, 0, 0);
    }
    __syncthreads();
  }
  int crowbase = mb * 128 + wm * 64;
  int ccolbase = nb * 128 + wn * 64;
#pragma unroll
  for (int mt = 0; mt < 4; ++mt)
#pragma unroll
    for (int nt = 0; nt < 4; ++nt) {
      int col = ccolbase + nt * 16 + (lane & 15);
#pragma unroll
      for (int r = 0; r < 4; ++r) {
        int row = crowbase + mt * 16 + ((lane >> 4) << 2) + r;
        C[(size_t)row * 4096 + col] = f2bf(acc[mt][nt][r]);
      }
    }
}

// ---------- phase 2: persistent sequential LSTM ----------
// Two INDEPENDENT 128-WG systems (batch halves never interact; rows disjoint).
// ROLLING h buffer: slot t is written exactly once per launch (during step t-1)
// and read only after the step-(t-1) barrier. No address reuse within a launch
// -> normal CACHED h loads can never hit a stale L2 line (lines enter L2 only
// post-release). Cross-launch lines hold bitwise-identical values
// (deterministic recompute), and dispatch-boundary acquire handles poison.
// h stores: LDS-staged, 32x dwordx4 sc0 sc1 per WG (write-through -> L2 never
// dirty -> no wbl2 anywhere). Flags: R2-proven protocol, per-half + backoff.
__global__ __launch_bounds__(256) void lstm_seq(const u16* __restrict__ xproj,
                                                const u16* __restrict__ Whb,
                                                const float* __restrict__ bias,
                                                u16* __restrict__ hroll,
                                                u32* __restrict__ flags,
                                                float* __restrict__ out) {
  __shared__ float pacc[16 * 272];  // padded rows (17 floats)
  __shared__ __align__(16) u16 hstage[32 * 8];
#define PIDX(frag, row, col) (((frag) * 272) + (row) * 17 + (col))
  int wg = blockIdx.x;
  int bh = wg >> 7;       // batch half (independent barrier domain)
  int hs = wg & 127;      // h-col slice (8 cols)
  int tid = threadIdx.x;
  int lane = tid & 63;
  int w = tid >> 6;       // wave -> K-slice
  int kw = w << 8;        // k base (256 per wave)
  int hi8 = (lane >> 4) << 3;

  // preload Wh fragments (register-resident for all 512 steps)
  bf16x8 wf[2][8];
#pragma unroll
  for (int nt = 0; nt < 2; ++nt) {
    int c = nt * 16 + (lane & 15);
    int wrow = ((c >> 3) << 10) + (hs << 3) + (c & 7);  // gate*1024 + hs*8 + jj
#pragma unroll
    for (int ks = 0; ks < 8; ++ks)
      wf[nt][ks] = *(const bf16x8*)&Whb[(size_t)wrow * 1024 + kw + ks * 32 + hi8];
  }

  int b = tid >> 3;                  // 0..31 batch row within half
  int jj = tid & 7;                  // h-col within slice
  int hrow = (bh << 5) + b;
  int hcol = (hs << 3) + jj;
  float bs0 = bias[hcol], bs1 = bias[1024 + hcol], bs2 = bias[2048 + hcol], bs3 = bias[3072 + hcol];
  float c_state = 0.f;
  int am_row0 = (bh << 5) + (lane & 15);
  int am_row1 = am_row0 + 16;
  int mI = b >> 4, r16 = b & 15;
  u32* myflags = flags + (bh << 7);  // 128 dwords for this half

  for (int t = 0; t < T_LEN; ++t) {
    const u16* hcur = hroll + (size_t)t * 65536;  // rolling slot
    // xproj: normal cached loads (immutable stream)
    const u16* xp = xproj + ((size_t)(t * 64 + hrow)) * 4096;
    u16 xp0 = xp[hcol], xp1 = xp[1024 + hcol], xp2 = xp[2048 + hcol], xp3 = xp[3072 + hcol];

    // h loads: NORMAL CACHED (safe: virgin addresses this launch, see header)
    const u16* p0 = hcur + (size_t)am_row0 * 1024 + kw + hi8;
    const u16* p1 = hcur + (size_t)am_row1 * 1024 + kw + hi8;
    bf16x8 a0s[8], a1s[8];
#pragma unroll
    for (int ks = 0; ks < 8; ++ks) {
      a0s[ks] = *(const bf16x8*)(p0 + ks * 32);
      a1s[ks] = *(const bf16x8*)(p1 + ks * 32);
    }

    f32x4 acc00 = f32x4{0.f, 0.f, 0.f, 0.f}, acc01 = acc00, acc10 = acc00, acc11 = acc00;
#pragma unroll
    for (int ks = 0; ks < 8; ++ks) {
      acc00 = __builtin_amdgcn_mfma_f32_16x16x32_bf16(a0s[ks], wf[0][ks], acc00, 0, 0, 0);
      acc01 = __builtin_amdgcn_mfma_f32_16x16x32_bf16(a0s[ks], wf[1][ks], acc01, 0, 0, 0);
      acc10 = __builtin_amdgcn_mfma_f32_16x16x32_bf16(a1s[ks], wf[0][ks], acc10, 0, 0, 0);
      acc11 = __builtin_amdgcn_mfma_f32_16x16x32_bf16(a1s[ks], wf[1][ks], acc11, 0, 0, 0);
    }
    // per-wave partials -> LDS (padded)
    {
      int rbase = ((lane >> 4) << 2);
      int cidx = lane & 15;
#pragma unroll
      for (int r = 0; r < 4; ++r) {
        pacc[PIDX(w * 4 + 0, rbase + r, cidx)] = acc00[r];
        pacc[PIDX(w * 4 + 1, rbase + r, cidx)] = acc01[r];
        pacc[PIDX(w * 4 + 2, rbase + r, cidx)] = acc10[r];
        pacc[PIDX(w * 4 + 3, rbase + r, cidx)] = acc11[r];
      }
    }
    __syncthreads();
    float g[4];
#pragma unroll
    for (int gate = 0; gate < 4; ++gate) {
      int cc = gate * 8 + jj;
      int nt = cc >> 4, c16 = cc & 15;
      float s = 0.f;
#pragma unroll
      for (int w2 = 0; w2 < 4; ++w2)
        s += pacc[PIDX(w2 * 4 + mI * 2 + nt, r16, c16)];
      g[gate] = s;
    }
    float gi = g[0] + bf2f(xp0) + bs0;
    float gf = g[1] + bf2f(xp1) + bs1;
    float go = g[2] + bf2f(xp2) + bs2;
    float gc = g[3] + bf2f(xp3) + bs3;
    float iv = 1.f / (1.f + __expf(-gi));
    float fv = 1.f / (1.f + __expf(-gf));
    float ov = 1.f / (1.f + __expf(-go));
    float cv = tanhf(gc);
    c_state = 1.f / (1.f + __expf(-(fv * c_state + iv * cv)));  // nonstandard, per reference
    float hn = tanhf(c_state) * ov;

    if (t == T_LEN - 1) {
      out[(size_t)hrow * 1024 + hcol] = hn;
    } else {
      // stage h row-slices in LDS, then 32 wide write-through stores
      hstage[b * 8 + jj] = f2bf(hn);
      __syncthreads();  // hstage visible + pacc reads done
      if (tid < 32) {
        u32x4 hv = *(const u32x4*)&hstage[tid * 8];
        u16* hdst = hroll + (size_t)(t + 1) * 65536 + (size_t)((bh << 5) + tid) * 1024 + (hs << 3);
        asm volatile("global_store_dwordx4 %0, %1, off sc0 sc1\n\t"
                     "s_waitcnt vmcnt(0)" :: "v"(hdst), "v"(hv) : "memory");
      }
      __syncthreads();  // wave0 stores drained before flag
      u32 tgt = (u32)(t + 1);
      if (tid == 0) {
        u32* fp = myflags + hs;
        asm volatile("global_store_dword %0, %1, off sc0 sc1" :: "v"(fp), "v"(tgt) : "memory");
      }
      if (tid < 64) {
        const u32* fp = myflags + (tid << 1);
        for (;;) {
          u32x2 f;
          asm volatile("global_load_dwordx2 %0, %1, off sc0 sc1\n\ts_waitcnt vmcnt(0)"
                       : "=v"(f) : "v"(fp) : "memory");
          if (__all((f[0] >= tgt) && (f[1] >= tgt))) break;
          __builtin_amdgcn_s_sleep(1);
        }
      }
      __syncthreads();
    }
  }
}

extern "C" void kernel_launch(void* const* d_in, const int* in_sizes, int n_in,
                              void* d_out, int out_size, void* d_ws, size_t ws_size,
                              hipStream_t stream) {
  const float* x  = (const float*)d_in[0];   // [512][64][1024]
  const float* Wx = (const float*)d_in[1];   // [4][1024][1024]
  const float* bx = (const float*)d_in[2];   // [4][1024]
  const float* Wh = (const float*)d_in[3];   // [4][1024][1024]
  const float* bh = (const float*)d_in[4];   // [4][1024]
  float* out = (float*)d_out;                // [64][1024]
  char* ws = (char*)d_ws;

  u16* wx_bf  = (u16*)(ws + OFF_WX);
  u16* wh_bf  = (u16*)(ws + OFF_WH);
  float* bias = (float*)(ws + OFF_BIAS);
  u32* flags  = (u32*)(ws + OFF_FLAGS);
  u16* hroll  = (u16*)(ws + OFF_HROLL);
  u16* x_bf   = (u16*)(ws + OFF_XBF);
  u16* xproj  = (u16*)(ws + OFF_XPROJ);

  // per-launch: zero flags (1 KiB) and rolling slot 0 (h_0 = 0, 128 KiB)
  hipMemsetAsync(ws + OFF_FLAGS, 0, 1024, stream);
  hipMemsetAsync(ws + OFF_HROLL, 0, 131072, stream);

  cvt_f32_bf16<<<4096, 256, 0, stream>>>(Wx, wx_bf, 4194304);
  cvt_f32_bf16<<<4096, 256, 0, stream>>>(Wh, wh_bf, 4194304);
  bias_add<<<16, 256, 0, stream>>>(bx, bh, bias);
  cvt_f32_bf16<<<32768, 256, 0, stream>>>(x, x_bf, 33554432);
  gemm_xproj<<<8192, 256, 0, stream>>>(x_bf, wx_bf, xproj);
  lstm_seq<<<256, 256, 0, stream>>>(xproj, wh_bf, bias, hroll, flags, out);
}